// Round 9
// baseline (72.611 us; speedup 1.0000x reference)
//
#include <hip/hip_runtime.h>
#include <stdint.h>

#define D_M   1024
#define L_OBS 2048
#define ALPHA 8192
#define D_H   2048

typedef __attribute__((ext_vector_type(8))) short short8;
typedef __attribute__((ext_vector_type(4))) float f32x4;

__device__ inline unsigned short f2bf(float f) {
  union { float f; unsigned u; } c; c.f = f;
  unsigned u = c.u;
  u += 0x7fffu + ((u >> 16) & 1u);   // round-to-nearest-even
  return (unsigned short)(u >> 16);
}

// ---------------- Kernel 1: scatter + forward-fill, one row per block --------
__global__ __launch_bounds__(1024) void impute_fill(
    const float* __restrict__ x_ts, const int* __restrict__ t_ts,
    const float* __restrict__ gmean, unsigned short* __restrict__ dst,
    int transposed_out) {
  __shared__ unsigned long long pack[ALPHA];   // 64 KB; 0 = no observation
  __shared__ float s_wv[16];
  __shared__ int   s_wh[16];

  const int m    = blockIdx.x;
  const int tid  = threadIdx.x;
  const int lane = tid & 63;
  const int wv   = tid >> 6;

  #pragma unroll
  for (int i = 0; i < 8; ++i) pack[tid + i * 1024] = 0ull;
  __syncthreads();

  #pragma unroll
  for (int j = 0; j < 2; ++j) {
    const int l = tid + j * 1024;
    const float xv = x_ts[(size_t)m * L_OBS + l];
    const int   tv = t_ts[(size_t)m * L_OBS + l];
    if ((xv == xv) && (tv >= 0) && (tv < ALPHA)) {
      union { float f; unsigned u; } c; c.f = xv;
      atomicMax(&pack[tv], ((unsigned long long)(l + 1) << 32) | c.u);
    }
  }
  __syncthreads();

  const int base = tid * 8;
  int has = 0; float lv = 0.f;
  #pragma unroll
  for (int i = 0; i < 8; ++i) {
    const unsigned long long p = pack[base + i];
    if (p >> 32) { has = 1; lv = __uint_as_float((unsigned)p); }
  }

  int ihas = has; float ilv = lv;
  #pragma unroll
  for (int d = 1; d < 64; d <<= 1) {
    const float pv = __shfl_up(ilv, d, 64);
    const int   ph = __shfl_up(ihas, d, 64);
    if (lane >= d && !ihas) { ihas = ph; ilv = pv; }
  }
  if (lane == 63) { s_wh[wv] = ihas; s_wv[wv] = ilv; }
  __syncthreads();
  if (wv == 0 && lane < 16) {
    int h2 = s_wh[lane]; float v2 = s_wv[lane];
    #pragma unroll
    for (int d = 1; d < 16; d <<= 1) {
      const float pv = __shfl_up(v2, d, 16);
      const int   ph = __shfl_up(h2, d, 16);
      if (lane >= d && !h2) { h2 = ph; v2 = pv; }
    }
    s_wh[lane] = h2; s_wv[lane] = v2;
  }
  __syncthreads();

  const float xlv = __shfl_up(ilv, 1, 64);
  const int   xh_ = __shfl_up(ihas, 1, 64);
  const int   xhas = (lane > 0) ? xh_ : 0;
  float running;
  if (xhas)                         running = xlv;
  else if (wv > 0 && s_wh[wv - 1])  running = s_wv[wv - 1];
  else                              running = gmean[m];

  if (transposed_out) {
    #pragma unroll
    for (int i = 0; i < 8; ++i) {
      const unsigned long long p = pack[base + i];
      if (p >> 32) running = __uint_as_float((unsigned)p);
      dst[(size_t)(base + i) * D_M + m] = f2bf(running);
    }
  } else {
    short8 ov;
    #pragma unroll
    for (int i = 0; i < 8; ++i) {
      const unsigned long long p = pack[base + i];
      if (p >> 32) running = __uint_as_float((unsigned)p);
      ov[i] = (short)f2bf(running);
    }
    *(short8*)&dst[(size_t)m * ALPHA + base] = ov;
  }
}

// ---------------- Kernel 1b: transpose reg[m][a] -> regT[a][m] ---------------
__global__ __launch_bounds__(256) void transpose_bf(
    const unsigned short* __restrict__ reg, unsigned short* __restrict__ regT) {
  __shared__ unsigned short tile[64 * 64];
  const int t  = threadIdx.x;
  const int m0 = (blockIdx.x & 15) * 64;
  const int A0 = (blockIdx.x >> 4) * 64;

  #pragma unroll
  for (int i = 0; i < 2; ++i) {
    const int m  = i * 32 + (t >> 3);
    const int ao = (t & 7) * 8;
    short8 v = *(const short8*)&reg[(size_t)(m0 + m) * ALPHA + A0 + ao];
    const int s = ((m & 7) ^ (m >> 3)) << 3;
    *(short8*)&tile[m * 64 + (ao ^ s)] = v;
  }
  __syncthreads();
  #pragma unroll
  for (int i = 0; i < 2; ++i) {
    const int a  = i * 32 + (t >> 3);
    const int mo = (t & 7) * 8;
    short8 ov;
    #pragma unroll
    for (int j = 0; j < 8; ++j) {
      const int mm = mo + j;
      const int s  = ((mm & 7) ^ (mm >> 3)) << 3;
      ov[j] = (short)tile[mm * 64 + (a ^ s)];
    }
    *(short8*)&regT[(size_t)(A0 + a) * D_M + m0 + mo] = ov;
  }
}

// ---------------- Kernel 2: W f32 -> bf16 ------------------------------------
__global__ __launch_bounds__(256) void wconv(const float* __restrict__ W,
                                             unsigned short* __restrict__ Wb) {
  const int i = (blockIdx.x * 256 + threadIdx.x) * 4;
  const float4 w = *reinterpret_cast<const float4*>(&W[i]);
  ushort4 o;
  o.x = f2bf(w.x); o.y = f2bf(w.y); o.z = f2bf(w.z); o.w = f2bf(w.w);
  *reinterpret_cast<ushort4*>(&Wb[i]) = o;
}

// ---------------- Kernel 3: 128x128 GEMM, 3 blocks/CU ------------------------
// out[a][h] = sum_m regT[a][m] * Wb[h][m] + b[h];  M=8192 N=2048 K=1024.
// R8 lesson: occupancy is the binding lever (2 blk/CU: 54->48.5us). Push to
// 3 blocks/CU: tile 128x128, 4 waves (256 thr), 3-slot BK=32 ring = 48 KB
// (3 x 48 = 144 <= 160), lb(256,3) -> 12 waves/CU. Depth-2 prefetch,
// counted vmcnt(4) steady (wait tile t+1 only; t+2's 4 loads stay in
// flight; issue-to-use ~2 tiles > HBM latency). 4 waves = 2M x 2N, 64x64
// per wave (acc 4x4 f32x4).
#define GNT3 32   // K-tiles (BK=32)

__device__ inline void gload_lds16(const void* g, void* l) {
  __builtin_amdgcn_global_load_lds(
      (const __attribute__((address_space(1))) unsigned int*)g,
      (__attribute__((address_space(3))) unsigned int*)l, 16, 0, 0);
}

#define BARX() { asm volatile("" ::: "memory"); __builtin_amdgcn_s_barrier(); \
                 asm volatile("" ::: "memory"); }
#define LGKM0() asm volatile("s_waitcnt lgkmcnt(0)" ::: "memory")
#define SB0()   __builtin_amdgcn_sched_barrier(0)

__global__ __launch_bounds__(256, 3) void gemm_bias(
    const unsigned short* __restrict__ A,   // regT [ALPHA][D_M]
    const unsigned short* __restrict__ B,   // Wb   [D_H][D_M]
    const float* __restrict__ bias, float* __restrict__ out) {
  __shared__ char lds[49152];               // A: 3 x 8KB @0; B: 3 x 8KB @24576

  const int tid  = threadIdx.x;
  const int lane = tid & 63;
  const int wid  = tid >> 6;                // 0..3
  const int wm   = wid >> 1;                // 0..1  (64-row half of 128)
  const int wn   = wid & 1;                 // 0..1  (64-col half of 128)
  const int bn   = blockIdx.x & 15;         // D_H/128 = 16; XCD = bid%8
  const int bm   = blockIdx.x >> 4;         // 0..63
  const int a0r = bm * 128, h0 = bn * 128;

  f32x4 acc[4][4] = {};
  short8 af[4], bf[4];

  // ---- staging: linear LDS dest (tid*16), inverse-swizzled global source
  const int r0 = tid >> 2, s0 = tid & 3;    // r0 0..63
  const int swzB = (s0 ^ ((r0 >> 1) & 3)) * 16;        // R4 0-conflict form
  const char* Asrc0 = (const char*)A + ((size_t)(a0r + r0) * D_M) * 2 + swzB;
  const char* Asrc1 = Asrc0 + (size_t)64 * D_M * 2;    // rows +64 (swz invariant)
  const char* Bsrc0 = (const char*)B + ((size_t)(h0 + r0) * D_M) * 2 + swzB;
  const char* Bsrc1 = Bsrc0 + (size_t)64 * D_M * 2;

#define STAGE(S, kt) { \
  char* ad_ = lds + (S) * 8192 + tid * 16; \
  gload_lds16(Asrc0 + (size_t)(kt) * 64, ad_); \
  gload_lds16(Asrc1 + (size_t)(kt) * 64, ad_ + 4096); \
  char* bd_ = lds + 24576 + (S) * 8192 + tid * 16; \
  gload_lds16(Bsrc0 + (size_t)(kt) * 64, bd_); \
  gload_lds16(Bsrc1 + (size_t)(kt) * 64, bd_ + 4096); }

  // ---- fragment read offsets (same involutive swizzle)
  const int rl  = lane & 15;
  const int rsw = (((lane >> 4) ^ ((rl >> 1) & 3))) * 16;
  const int Aro = (wm * 64 + rl) * 64 + rsw;            // + mf*1024 + S*8192
  const int Bro = 24576 + (wn * 64 + rl) * 64 + rsw;    // + nf*1024 + S*8192

#define TILE(S, SST, T) { \
  _Pragma("unroll") \
  for (int mf = 0; mf < 4; ++mf) \
    af[mf] = *(const short8*)(lds + (S) * 8192 + Aro + mf * 1024); \
  _Pragma("unroll") \
  for (int nf = 0; nf < 4; ++nf) \
    bf[nf] = *(const short8*)(lds + (S) * 8192 + Bro + nf * 1024); \
  if ((T) < GNT3 - 2) STAGE(SST, (T) + 2); \
  LGKM0(); SB0(); \
  __builtin_amdgcn_s_setprio(1); \
  _Pragma("unroll") \
  for (int mf = 0; mf < 4; ++mf) \
    _Pragma("unroll") \
    for (int nf = 0; nf < 4; ++nf) \
      acc[mf][nf] = __builtin_amdgcn_mfma_f32_16x16x32_bf16(af[mf], bf[nf], acc[mf][nf], 0, 0, 0); \
  __builtin_amdgcn_s_setprio(0); \
  if ((T) < GNT3 - 2)       { asm volatile("s_waitcnt vmcnt(4)" ::: "memory"); } \
  else if ((T) == GNT3 - 2) { asm volatile("s_waitcnt vmcnt(0)" ::: "memory"); } \
  if ((T) < GNT3 - 1) BARX(); }

  // ---- prologue: tiles 0,1 staged; wait tile 0 (leave tile 1 in flight)
  STAGE(0, 0); STAGE(1, 1);
  asm volatile("s_waitcnt vmcnt(4)" ::: "memory");
  BARX();

  // ---- K-loop: 3-slot ring, unroll by 3; t = 0..29 stage t+2 (max 31)
  for (int tt = 0; tt < GNT3 - 2; tt += 3) {
    TILE(0, 2, tt);
    TILE(1, 0, tt + 1);
    TILE(2, 1, tt + 2);
  }
  TILE(0, 2, 30);   // slot 30%3=0; no stage (T>=30)
  TILE(1, 0, 31);   // slot 31%3=1; no stage, no barrier

  // ---- epilogue: C row = (lane>>4)*4 + r (A side), col = lane&15 (B side)
  const int cl = lane & 15, rq = lane >> 4;
  #pragma unroll
  for (int nf = 0; nf < 4; ++nf) {
    const int h = h0 + wn * 64 + nf * 16 + cl;
    const float bv = bias[h];
    #pragma unroll
    for (int mf = 0; mf < 4; ++mf) {
      const int ar = a0r + wm * 64 + mf * 16 + rq * 4;
      #pragma unroll
      for (int r = 0; r < 4; ++r)
        out[(size_t)(ar + r) * D_H + h] = acc[mf][nf][r] + bv;
    }
  }
#undef STAGE
#undef TILE
}

extern "C" void kernel_launch(void* const* d_in, const int* in_sizes, int n_in,
                              void* d_out, int out_size, void* d_ws, size_t ws_size,
                              hipStream_t stream) {
  const float* x  = (const float*)d_in[0];
  const int*   t  = (const int*)d_in[1];
  const float* gm = (const float*)d_in[2];
  const float* W  = (const float*)d_in[3];
  const float* b  = (const float*)d_in[4];
  float* out = (float*)d_out;

  const size_t SZ_REG = (size_t)ALPHA * D_M * 2;   // 16 MB
  const size_t SZ_WB  = (size_t)D_H * D_M * 2;     //  4 MB

  if (ws_size >= 2 * SZ_REG + SZ_WB) {
    unsigned short* reg  = (unsigned short*)d_ws;
    unsigned short* regT = (unsigned short*)((char*)d_ws + SZ_REG);
    unsigned short* Wb   = (unsigned short*)((char*)d_ws + 2 * SZ_REG);
    impute_fill<<<D_M, 1024, 0, stream>>>(x, t, gm, reg, 0);
    wconv<<<(D_H * D_M) / 1024, 256, 0, stream>>>(W, Wb);
    transpose_bf<<<(ALPHA / 64) * (D_M / 64), 256, 0, stream>>>(reg, regT);
    gemm_bias<<<(ALPHA / 128) * (D_H / 128), 256, 0, stream>>>(regT, Wb, b, out);
  } else {
    unsigned short* regT = (unsigned short*)d_ws;
    unsigned short* Wb   = (unsigned short*)((char*)d_ws + SZ_REG);
    impute_fill<<<D_M, 1024, 0, stream>>>(x, t, gm, regT, 1);
    wconv<<<(D_H * D_M) / 1024, 256, 0, stream>>>(W, Wb);
    gemm_bias<<<(ALPHA / 128) * (D_H / 128), 256, 0, stream>>>(regT, Wb, b, out);
  }
}